// Round 10
// baseline (71.014 us; speedup 1.0000x reference)
//
#include <hip/hip_runtime.h>
#include <math.h>

#define BN 256
#define RPC 64        // rows per chunk
#define ABLOCK 256

// 6-op DPP wave64 sum: result valid in lane 63 (VALU only, no DS pipe)
__device__ __forceinline__ float dpp_red63(float x) {
  x += __int_as_float(__builtin_amdgcn_update_dpp(0, __float_as_int(x), 0x111, 0xf, 0xf, true)); // row_shr:1
  x += __int_as_float(__builtin_amdgcn_update_dpp(0, __float_as_int(x), 0x112, 0xf, 0xf, true)); // row_shr:2
  x += __int_as_float(__builtin_amdgcn_update_dpp(0, __float_as_int(x), 0x114, 0xf, 0xf, true)); // row_shr:4
  x += __int_as_float(__builtin_amdgcn_update_dpp(0, __float_as_int(x), 0x118, 0xf, 0xf, true)); // row_shr:8
  x += __int_as_float(__builtin_amdgcn_update_dpp(0, __float_as_int(x), 0x142, 0xf, 0xf, true)); // row_bcast:15
  x += __int_as_float(__builtin_amdgcn_update_dpp(0, __float_as_int(x), 0x143, 0xf, 0xf, true)); // row_bcast:31
  return x;
}

__device__ __forceinline__ float bcast63(float x) {
  return __int_as_float(__builtin_amdgcn_readlane(__float_as_int(x), 63));
}

template<int P, int Q>
__device__ __forceinline__ void jrot(float K[3][3], float V[3][3]) {
  float apq = K[P][Q];
  if (apq == 0.f) return;
  float app = K[P][P], aqq = K[Q][Q];
  float tau = (aqq - app) / (2.f * apq);
  float st = sqrtf(1.f + tau * tau);
  float tt = (tau >= 0.f) ? 1.f / (tau + st) : 1.f / (tau - st);
  float c = 1.f / sqrtf(1.f + tt * tt);
  float s = tt * c;
#pragma unroll
  for (int k = 0; k < 3; k++) { float kp = K[k][P], kq = K[k][Q]; K[k][P] = c * kp - s * kq; K[k][Q] = s * kp + c * kq; }
#pragma unroll
  for (int k = 0; k < 3; k++) { float kp = K[P][k], kq = K[Q][k]; K[P][k] = c * kp - s * kq; K[Q][k] = s * kp + c * kq; }
#pragma unroll
  for (int k = 0; k < 3; k++) { float vp = V[k][P], vq = V[k][Q]; V[k][P] = c * vp - s * vq; V[k][Q] = s * vp + c * vq; }
}

template<int A, int C>
__device__ __forceinline__ void cswap(float lam[3], float V[3][3]) {
  if (lam[A] < lam[C]) {
    float tl = lam[A]; lam[A] = lam[C]; lam[C] = tl;
#pragma unroll
    for (int k = 0; k < 3; k++) { float tv = V[k][A]; V[k][A] = V[k][C]; V[k][C] = tv; }
  }
}

__device__ __forceinline__ void acc4(float4& T, float s, const float4& e) {
  T.x += s * e.x; T.y += s * e.y; T.z += s * e.z; T.w += s * e.w;
}

__device__ __forceinline__ float dot4(const float4& a, const float4& b) {
  return a.x * b.x + a.y * b.y + a.z * b.z + a.w * b.w;
}

// ---------- kernel A: per-(batch, 64-row-chunk) partial sums ----------
extern "C" __global__ void __launch_bounds__(ABLOCK, 5)
svd_partial(const float* __restrict__ src, const float* __restrict__ tgt,
            const float* __restrict__ scores, const int* __restrict__ idx0,
            float* __restrict__ ws)
{
  __shared__ __align__(16) float Af[6][BN];   // [0..2]=cnt*tgt_d, [3..5]=tgt_d
  __shared__ __align__(16) float kxv[RPC][4]; // {x0,x1,x2,vf} for this chunk's rows
  __shared__ float vm[BN];
  __shared__ int cnt[BN];
  __shared__ float wsum[4][24];

  const int t = threadIdx.x;
  const int bc = blockIdx.x;     // b*4 + chunk
  const int b = bc >> 2;
  const int row0 = (bc & 3) * RPC;
  const int lane = t & 63;
  const int wave = t >> 6;

  cnt[t] = 0;
  __syncthreads();

  {
    int id = idx0[b * BN + t];               // values in [0,256]; 256 == SENTINEL
    int valid = ((unsigned)id < 256u);
    vm[t] = valid ? 1.f : 0.f;
    if (valid) atomicAdd(&cnt[id], 1);
    const float* tb = tgt + (size_t)b * 3 * BN;
    Af[3][t] = tb[t]; Af[4][t] = tb[BN + t]; Af[5][t] = tb[2 * BN + t];
  }
  if (t < RPC) {
    const float* sb = src + (size_t)b * 3 * BN + row0;
    kxv[t][0] = sb[t]; kxv[t][1] = sb[BN + t]; kxv[t][2] = sb[2 * BN + t];
  }
  __syncthreads();
  {
    float cf = (float)cnt[t];
    Af[0][t] = cf * Af[3][t];
    Af[1][t] = cf * Af[4][t];
    Af[2][t] = cf * Af[5][t];
  }
  if (t < RPC) kxv[t][3] = vm[row0 + t];
  __syncthreads();

  // prologue partials over this chunk's 64 rows (wave 0, one row per lane)
  if (wave == 0) {
    float4 kv = *(const float4*)&kxv[lane][0];
    float rr[7];
    rr[0] = kv.w;                                       // M
    rr[1] = kv.w * kv.x; rr[2] = kv.w * kv.y; rr[3] = kv.w * kv.z;  // Sxv
    rr[4] = kv.x; rr[5] = kv.y; rr[6] = kv.z;           // Sxf
#pragma unroll
    for (int k = 0; k < 7; k++) rr[k] = dpp_red63(rr[k]);
    if (lane == 63) {
      float* wp = ws + (size_t)bc * 32;
      wp[30] = rr[0];
      wp[24] = rr[1]; wp[25] = rr[2]; wp[26] = rr[3];
      wp[27] = rr[4]; wp[28] = rr[5]; wp[29] = rr[6];
    }
  }

  const int j0 = lane * 4;
  const float* wbase = scores + ((size_t)b * BN + row0 + wave * 16) * BN + j0;

  float4 Tv0 = {0,0,0,0}, Tv1 = {0,0,0,0}, Tv2 = {0,0,0,0}, Tv3 = {0,0,0,0};
  float4 Tf0 = {0,0,0,0}, Tf1 = {0,0,0,0}, Tf2 = {0,0,0,0}, Tf3 = {0,0,0,0};

  float4 c0 = *(const float4*)(wbase);
  float4 c1 = *(const float4*)(wbase + (size_t)BN);
  float4 c2 = *(const float4*)(wbase + (size_t)2 * BN);
  float4 c3 = *(const float4*)(wbase + (size_t)3 * BN);

#pragma unroll 1
  for (int g = 0; g < 4; g++) {
    const int gn = (g < 3) ? (g + 1) : 3;   // clamp: last iter re-loads (cache hit)
    float4 n0 = *(const float4*)(wbase + (size_t)(4 * gn) * BN);
    float4 n1 = *(const float4*)(wbase + (size_t)(4 * gn + 1) * BN);
    float4 n2 = *(const float4*)(wbase + (size_t)(4 * gn + 2) * BN);
    float4 n3 = *(const float4*)(wbase + (size_t)(4 * gn + 3) * BN);
    __builtin_amdgcn_sched_barrier(0);

    c0.x = __expf(c0.x); c0.y = __expf(c0.y); c0.z = __expf(c0.z); c0.w = __expf(c0.w);
    c1.x = __expf(c1.x); c1.y = __expf(c1.y); c1.z = __expf(c1.z); c1.w = __expf(c1.w);
    c2.x = __expf(c2.x); c2.y = __expf(c2.y); c2.z = __expf(c2.z); c2.w = __expf(c2.w);
    c3.x = __expf(c3.x); c3.y = __expf(c3.y); c3.z = __expf(c3.z); c3.w = __expf(c3.w);
    float s0 = (c0.x + c0.y) + (c0.z + c0.w);
    float s1 = (c1.x + c1.y) + (c1.z + c1.w);
    float s2 = (c2.x + c2.y) + (c2.z + c2.w);
    float s3 = (c3.x + c3.y) + (c3.z + c3.w);
    s0 = dpp_red63(s0); s1 = dpp_red63(s1); s2 = dpp_red63(s2); s3 = dpp_red63(s3);
    float i0 = __builtin_amdgcn_rcpf(bcast63(s0));
    float i1 = __builtin_amdgcn_rcpf(bcast63(s1));
    float i2 = __builtin_amdgcn_rcpf(bcast63(s2));
    float i3 = __builtin_amdgcn_rcpf(bcast63(s3));

    const int pr = wave * 16 + 4 * g;
    {
      float4 kv = *(const float4*)&kxv[pr][0];
      float wf1 = i0 * kv.x, wf2 = i0 * kv.y, wf3 = i0 * kv.z, wv0 = kv.w * i0;
      acc4(Tf0, i0, c0);  acc4(Tf1, wf1, c0); acc4(Tf2, wf2, c0); acc4(Tf3, wf3, c0);
      acc4(Tv0, wv0, c0); acc4(Tv1, kv.w * wf1, c0); acc4(Tv2, kv.w * wf2, c0); acc4(Tv3, kv.w * wf3, c0);
    }
    {
      float4 kv = *(const float4*)&kxv[pr + 1][0];
      float wf1 = i1 * kv.x, wf2 = i1 * kv.y, wf3 = i1 * kv.z, wv0 = kv.w * i1;
      acc4(Tf0, i1, c1);  acc4(Tf1, wf1, c1); acc4(Tf2, wf2, c1); acc4(Tf3, wf3, c1);
      acc4(Tv0, wv0, c1); acc4(Tv1, kv.w * wf1, c1); acc4(Tv2, kv.w * wf2, c1); acc4(Tv3, kv.w * wf3, c1);
    }
    {
      float4 kv = *(const float4*)&kxv[pr + 2][0];
      float wf1 = i2 * kv.x, wf2 = i2 * kv.y, wf3 = i2 * kv.z, wv0 = kv.w * i2;
      acc4(Tf0, i2, c2);  acc4(Tf1, wf1, c2); acc4(Tf2, wf2, c2); acc4(Tf3, wf3, c2);
      acc4(Tv0, wv0, c2); acc4(Tv1, kv.w * wf1, c2); acc4(Tv2, kv.w * wf2, c2); acc4(Tv3, kv.w * wf3, c2);
    }
    {
      float4 kv = *(const float4*)&kxv[pr + 3][0];
      float wf1 = i3 * kv.x, wf2 = i3 * kv.y, wf3 = i3 * kv.z, wv0 = kv.w * i3;
      acc4(Tf0, i3, c3);  acc4(Tf1, wf1, c3); acc4(Tf2, wf2, c3); acc4(Tf3, wf3, c3);
      acc4(Tv0, wv0, c3); acc4(Tv1, kv.w * wf1, c3); acc4(Tv2, kv.w * wf2, c3); acc4(Tv3, kv.w * wf3, c3);
    }
    c0 = n0; c1 = n1; c2 = n2; c3 = n3;
  }

  // epilogue dots with this lane's A columns
  float acc[24];
  {
    float4 a6[6];
#pragma unroll
    for (int k = 0; k < 6; k++) a6[k] = *(const float4*)&Af[k][j0];
#pragma unroll
    for (int e = 0; e < 3; e++) {
      acc[0 + e]  = dot4(Tv1, a6[e]);
      acc[3 + e]  = dot4(Tv2, a6[e]);
      acc[6 + e]  = dot4(Tv3, a6[e]);
      acc[9 + e]  = dot4(Tf1, a6[3 + e]);
      acc[12 + e] = dot4(Tf2, a6[3 + e]);
      acc[15 + e] = dot4(Tf3, a6[3 + e]);
      acc[18 + e] = dot4(Tv0, a6[e]);
      acc[21 + e] = dot4(Tf0, a6[3 + e]);
    }
  }
#pragma unroll
  for (int k = 0; k < 24; k++) acc[k] = dpp_red63(acc[k]);
  if (lane == 63) {
#pragma unroll
    for (int k = 0; k < 24; k++) wsum[wave][k] = acc[k];
  }
  __syncthreads();
  if (t < 24) {
    float v = (wsum[0][t] + wsum[1][t]) + (wsum[2][t] + wsum[3][t]);
    ws[(size_t)bc * 32 + t] = v;
  }
}

// ---------- kernel B: one thread per batch does the 3x3 SVD ----------
extern "C" __global__ void svd_finalize(const float* __restrict__ ws,
                                        float* __restrict__ out, int NB)
{
  int b = blockIdx.x * blockDim.x + threadIdx.x;
  if (b >= NB) return;
  float s31[31];
#pragma unroll
  for (int k = 0; k < 31; k++) {
    const float* wp = ws + (size_t)b * 4 * 32 + k;
    s31[k] = (wp[0] + wp[32]) + (wp[64] + wp[96]);
  }

  float M = s31[30];
  float Minv = 1.f / fmaxf(M, 1.f);
  bool use_v = (M > 3.f);
  const float Ninv = 1.f / (float)BN;
  float H[3][3], mu[3];
#pragma unroll
  for (int d = 0; d < 3; d++) {
    mu[d] = use_v ? s31[24 + d] * Minv : s31[27 + d] * Ninv;
#pragma unroll
    for (int e = 0; e < 3; e++) {
      float hv = s31[d * 3 + e]     - s31[24 + d] * s31[18 + e] * Minv;
      float hf = s31[9 + d * 3 + e] - s31[27 + d] * s31[21 + e] * Ninv;
      H[d][e] = use_v ? hv : hf;
    }
  }
  float K[3][3];
#pragma unroll
  for (int i = 0; i < 3; i++)
#pragma unroll
    for (int j = 0; j < 3; j++) {
      float s_ = 0.f;
#pragma unroll
      for (int k = 0; k < 3; k++) s_ += H[k][i] * H[k][j];
      K[i][j] = s_;
    }
  float V[3][3] = {{1.f,0.f,0.f},{0.f,1.f,0.f},{0.f,0.f,1.f}};
  for (int sw = 0; sw < 8; sw++) { jrot<0,1>(K, V); jrot<0,2>(K, V); jrot<1,2>(K, V); }
  float lam[3] = {K[0][0], K[1][1], K[2][2]};
  cswap<0,1>(lam, V); cswap<1,2>(lam, V); cswap<0,1>(lam, V);

  float v1[3] = {V[0][0], V[1][0], V[2][0]};
  float v2[3] = {V[0][1], V[1][1], V[2][1]};
  float v3[3] = {V[0][2], V[1][2], V[2][2]};
  float u1[3], u2[3], u3[3];
#pragma unroll
  for (int i = 0; i < 3; i++) {
    u1[i] = H[i][0] * v1[0] + H[i][1] * v1[1] + H[i][2] * v1[2];
    u2[i] = H[i][0] * v2[0] + H[i][1] * v2[1] + H[i][2] * v2[2];
  }
  float n1s = u1[0]*u1[0] + u1[1]*u1[1] + u1[2]*u1[2];
  if (n1s > 1e-24f) { float r = 1.f / sqrtf(n1s); u1[0]*=r; u1[1]*=r; u1[2]*=r; }
  else { u1[0] = 1.f; u1[1] = 0.f; u1[2] = 0.f; }
  float d12 = u1[0]*u2[0] + u1[1]*u2[1] + u1[2]*u2[2];
  u2[0] -= d12 * u1[0]; u2[1] -= d12 * u1[1]; u2[2] -= d12 * u1[2];
  float n2s = u2[0]*u2[0] + u2[1]*u2[1] + u2[2]*u2[2];
  if (n2s > 1e-24f) { float r = 1.f / sqrtf(n2s); u2[0]*=r; u2[1]*=r; u2[2]*=r; }
  else {
    float ex_ = (fabsf(u1[0]) < 0.9f) ? 1.f : 0.f;
    float ey = 1.f - ex_;
    float cx = u1[1]*0.f - u1[2]*ey;
    float cy = u1[2]*ex_ - u1[0]*0.f;
    float cz = u1[0]*ey - u1[1]*ex_;
    float nn = 1.f / sqrtf(cx*cx + cy*cy + cz*cz + 1e-30f);
    u2[0] = cx*nn; u2[1] = cy*nn; u2[2] = cz*nn;
  }
  u3[0] = u1[1]*u2[2] - u1[2]*u2[1];
  u3[1] = u1[2]*u2[0] - u1[0]*u2[2];
  u3[2] = u1[0]*u2[1] - u1[1]*u2[0];
  float detV = v1[0]*(v2[1]*v3[2] - v2[2]*v3[1])
             - v1[1]*(v2[0]*v3[2] - v2[2]*v3[0])
             + v1[2]*(v2[0]*v3[1] - v2[1]*v3[0]);
  float f = (detV < 0.f) ? -1.f : 1.f;
  float R_[3][3];
#pragma unroll
  for (int i = 0; i < 3; i++)
#pragma unroll
    for (int k = 0; k < 3; k++)
      R_[i][k] = v1[i]*u1[k] + v2[i]*u2[k] + f * v3[i]*u3[k];

  float* Rout = out + (size_t)b * 9;
#pragma unroll
  for (int i = 0; i < 3; i++)
#pragma unroll
    for (int k = 0; k < 3; k++)
      Rout[i * 3 + k] = R_[i][k];
  float* Tout = out + (size_t)NB * 9 + (size_t)b * 3;
#pragma unroll
  for (int i = 0; i < 3; i++)
    Tout[i] = -(R_[i][0]*mu[0] + R_[i][1]*mu[1] + R_[i][2]*mu[2]);
}

extern "C" void kernel_launch(void* const* d_in, const int* in_sizes, int n_in,
                              void* d_out, int out_size, void* d_ws, size_t ws_size,
                              hipStream_t stream) {
  const float* src = (const float*)d_in[0];
  const float* tgt = (const float*)d_in[1];
  const float* scores = (const float*)d_in[2];
  const int* idx0 = (const int*)d_in[3];
  float* out = (float*)d_out;
  float* ws = (float*)d_ws;
  int NB = in_sizes[0] / (3 * BN);

  hipLaunchKernelGGL(svd_partial, dim3(NB * 4), dim3(ABLOCK), 0, stream,
                     src, tgt, scores, idx0, ws);
  hipLaunchKernelGGL(svd_finalize, dim3((NB + 255) / 256), dim3(256), 0, stream,
                     ws, out, NB);
}